// Round 16
// baseline (76.006 us; speedup 1.0000x reference)
//
#include <hip/hip_runtime.h>
#include <hip/hip_bf16.h>

#define ALPHA 0.2f
static __device__ __forceinline__ float lrel(float x) { return fmaxf(x, ALPHA * x); }

typedef __attribute__((ext_vector_type(8))) short bf16x8;
typedef __attribute__((ext_vector_type(4))) float f32x4;

union FragU { bf16x8 v; unsigned int u[4]; uint4 q; };

// VGPR-form MFMA via inline asm ("v" pins operands to arch VGPRs)
static __device__ __forceinline__ f32x4 mfma_init(bf16x8 a, bf16x8 b, f32x4 c) {
    f32x4 d;
    asm("v_mfma_f32_16x16x32_bf16 %0, %1, %2, %3" : "=&v"(d) : "v"(a), "v"(b), "v"(c));
    return d;
}
static __device__ __forceinline__ void mfma_acc(f32x4& acc, bf16x8 a, bf16x8 b) {
    asm("v_mfma_f32_16x16x32_bf16 %0, %1, %2, %0" : "+v"(acc) : "v"(a), "v"(b));
}

// pack two f32 -> one dword of 2 bf16 (RNE)
static __device__ __forceinline__ unsigned int pk2(float a, float b) {
    unsigned int r;
    asm("v_cvt_pk_bf16_f32 %0, %1, %2" : "=v"(r) : "v"(a), "v"(b));
    return r;
}
static __device__ __forceinline__ unsigned int cvl2(float a, float b) {
    return pk2(lrel(a), lrel(b));
}
// agg += lrel(x) as two FMAs: agg = 0.6x + 0.4|x| + agg (abs is a free VOP3 modifier)
static __device__ __forceinline__ void aggfma(float& agg, float x) {
    agg = fmaf(0.6f, x, fmaf(0.4f, fabsf(x), agg));
}
// f32 -> bf16 (RNE) scalar
static __device__ __forceinline__ unsigned short f2bf(float x) {
    union { float f; unsigned int u; } c;
    c.f = x;
    unsigned int r = c.u + 0x7FFFu + ((c.u >> 16) & 1u);
    return (unsigned short)(r >> 16);
}
// pi permutation on 64 features: slot(16nf+4a+r) -> 32(nf>>1)+8a+4(nf&1)+r
static __device__ __forceinline__ int pi64(int s) {
    return 32 * ((s >> 4) >> 1) + 8 * ((s >> 2) & 3) + 4 * ((s >> 4) & 1) + (s & 3);
}

// ---------------- Kernel 1: Upi = pi(x @ W0top + b0), x_bf, weight fragments ----------------
__global__ __launch_bounds__(256) void k_uv(
    const float* __restrict__ x, const float* __restrict__ W0, const float* __restrict__ b0,
    const float* __restrict__ W1, const float* __restrict__ W2,
    float* __restrict__ Upi, unsigned short* __restrict__ xbf, unsigned int* __restrict__ WF)
{
    if (blockIdx.x == 1024) {
        const int t = threadIdx.x;
        const int l = t & 63, part = t >> 6;
        const int lo = l & 15, g = l >> 4;
        for (int ff = part; ff < 20; ff += 4) {
            unsigned int o[4];
            if (ff < 4) {
                const int nf = ff;
                const int pc = 32 * (nf >> 1) + 8 * (lo >> 2) + 4 * (nf & 1) + (lo & 3);
#pragma unroll
                for (int uq = 0; uq < 4; ++uq) {
                    const int k0 = 8 * g + 2 * uq;
                    o[uq] = pk2(W0[(32 + k0) * 64 + pc], W0[(33 + k0) * 64 + pc]);
                }
            } else if (ff < 12) {
                const int s = (ff - 4) >> 2, nf = (ff - 4) & 3;
                const int pc = 32 * (nf >> 1) + 8 * (lo >> 2) + 4 * (nf & 1) + (lo & 3);
#pragma unroll
                for (int uq = 0; uq < 4; ++uq) {
                    const int k0 = 32 * s + 8 * g + 2 * uq;
                    o[uq] = pk2(W1[k0 * 64 + pc], W1[(k0 + 1) * 64 + pc]);
                }
            } else {
                const int s = (ff - 12) >> 2, nf = (ff - 12) & 3;
                const int c2 = 16 * nf + lo;
#pragma unroll
                for (int uq = 0; uq < 4; ++uq) {
                    const int k0 = 32 * s + 8 * g + 2 * uq;
                    o[uq] = pk2(W2[k0 * 64 + c2], W2[(k0 + 1) * 64 + c2]);
                }
            }
            *(uint4*)(WF + (ff * 64 + l) * 4) = make_uint4(o[0], o[1], o[2], o[3]);
        }
        return;
    }
    const int idx = blockIdx.x * 256 + threadIdx.x;
    const int n = idx >> 6;
    const int slot = idx & 63;
    const int f = pi64(slot);
    const float* xr = x + n * 32;
    float u = b0[f];
#pragma unroll
    for (int i = 0; i < 32; ++i) u += xr[i] * W0[i * 64 + f];
    Upi[idx] = u;
    if (slot < 32) xbf[n * 32 + slot] = f2bf(xr[slot]);
}

// ---------------- Kernel 2: edge MLP (all 3 layers on MFMA) + sum over j ----------------
// DUAL j-CHAINS per wave iteration: tiles 2k (A) and 2k+1 (B) of the SAME node.
// Weights/u0f/biases/agg shared; every MFMA cluster interleaves two independent
// init/acc chains -> per-wave dependent-latency exposure halves. W1+W2 stream
// from LDS (8 ds_reads serve 16 MFMAs); only W0 frags persist in registers.
__global__ __launch_bounds__(256, 2) void k_edge(
    const float* __restrict__ Upi, const unsigned short* __restrict__ xbf,
    const unsigned int* __restrict__ WF,
    const float* __restrict__ b1, const float* __restrict__ b2,
    float* __restrict__ AGG)
{
    __shared__ uint4 wlds[1024];  // [0..7]=W1 frags (s*4+nf), [8..15]=W2 frags
    const int tid = threadIdx.x;
    const int w = tid >> 6, l = tid & 63;
    const int lo = l & 15, g = l >> 4;
    const int bid = blockIdx.x;
    const int b = bid >> 7, ig = bid & 127;
    const int node = b * 512 + ig * 4 + w;

    // ---- stage W1/W2 fragments into LDS (once per block)
    for (int idx = tid; idx < 1024; idx += 256)
        wlds[idx] = ((const uint4*)WF)[256 + idx];

    // ---- W0bot fragments in registers
    FragU w0f[4];
    const uint4* wp = (const uint4*)WF;
#pragma unroll
    for (int nf = 0; nf < 4; ++nf) w0f[nf].q = wp[nf * 64 + l];

    // ---- per-i C-init for GEMM0 (Upi broadcast) + bias C-inits (shared by chains)
    f32x4 u0f[4], b1f[4], b2f[4];
#pragma unroll
    for (int nf = 0; nf < 4; ++nf) {
        const float4 t0 = *(const float4*)(Upi + node * 64 + nf * 16 + 4 * g);
        u0f[nf] = (f32x4){t0.x, t0.y, t0.z, t0.w};
        const float4 t1 = *(const float4*)(b1 + 32 * (nf >> 1) + 8 * g + 4 * (nf & 1));
        const float4 t2 = *(const float4*)(b2 + 16 * nf + 4 * g);
        b1f[nf] = (f32x4){t1.x, t1.y, t1.z, t1.w};
        b2f[nf] = (f32x4){t2.x, t2.y, t2.z, t2.w};
    }

    const unsigned short* xb = xbf + b * 512 * 32;

    // ---- prologue: xj frags for tiles 0 (chain A) and 1 (chain B)
    FragU xjA, xjB;
    xjA.q = *(const uint4*)(xb + lo * 32 + 8 * g);
    xjB.q = *(const uint4*)(xb + (16 + lo) * 32 + 8 * g);

    float aggL[4][4];
#pragma unroll
    for (int nf = 0; nf < 4; ++nf)
#pragma unroll
        for (int r = 0; r < 4; ++r) aggL[nf][r] = 0.f;

    __syncthreads();

#pragma unroll 1
    for (int k = 0; k < 16; ++k) {
        // opaque zero: defeats LICM on the LDS weight reads
        int widx = 0;
        asm volatile("" : "+v"(widx));

        // prefetch next pair's xj (tiles 2k+2, 2k+3; wraps harmlessly on last iter)
        const int jA = ((2 * k + 2) & 31) * 16;
        const int jB = ((2 * k + 3) & 31) * 16;
        FragU xjAn, xjBn;
        xjAn.q = *(const uint4*)(xb + (jA + lo) * 32 + 8 * g);
        xjBn.q = *(const uint4*)(xb + (jB + lo) * 32 + 8 * g);

        // ---- GEMM0 both chains (8 independent MFMAs)
        __builtin_amdgcn_s_setprio(1);
        f32x4 acc0A[4], acc0B[4];
#pragma unroll
        for (int nf = 0; nf < 4; ++nf) {
            acc0A[nf] = mfma_init(w0f[nf].v, xjA.v, u0f[nf]);
            acc0B[nf] = mfma_init(w0f[nf].v, xjB.v, u0f[nf]);
        }
        __builtin_amdgcn_s_setprio(0);

        // ---- pack q for both chains
        FragU qA0, qA1, qB0, qB1;
        qA0.u[0] = cvl2(acc0A[0][0], acc0A[0][1]);
        qA0.u[1] = cvl2(acc0A[0][2], acc0A[0][3]);
        qA0.u[2] = cvl2(acc0A[1][0], acc0A[1][1]);
        qA0.u[3] = cvl2(acc0A[1][2], acc0A[1][3]);
        qA1.u[0] = cvl2(acc0A[2][0], acc0A[2][1]);
        qA1.u[1] = cvl2(acc0A[2][2], acc0A[2][3]);
        qA1.u[2] = cvl2(acc0A[3][0], acc0A[3][1]);
        qA1.u[3] = cvl2(acc0A[3][2], acc0A[3][3]);
        qB0.u[0] = cvl2(acc0B[0][0], acc0B[0][1]);
        qB0.u[1] = cvl2(acc0B[0][2], acc0B[0][3]);
        qB0.u[2] = cvl2(acc0B[1][0], acc0B[1][1]);
        qB0.u[3] = cvl2(acc0B[1][2], acc0B[1][3]);
        qB1.u[0] = cvl2(acc0B[2][0], acc0B[2][1]);
        qB1.u[1] = cvl2(acc0B[2][2], acc0B[2][3]);
        qB1.u[2] = cvl2(acc0B[3][0], acc0B[3][1]);
        qB1.u[3] = cvl2(acc0B[3][2], acc0B[3][3]);

        // ---- GEMM1 both chains (W1 from LDS; each ds_read serves 2 MFMAs)
        __builtin_amdgcn_s_setprio(1);
        f32x4 acc1A[4], acc1B[4];
#pragma unroll
        for (int nf = 0; nf < 4; ++nf) {
            FragU wa, wb;
            wa.q = wlds[widx + nf * 64 + l];
            wb.q = wlds[widx + (4 + nf) * 64 + l];
            acc1A[nf] = mfma_init(wa.v, qA0.v, b1f[nf]);
            acc1B[nf] = mfma_init(wa.v, qB0.v, b1f[nf]);
            mfma_acc(acc1A[nf], wb.v, qA1.v);
            mfma_acc(acc1B[nf], wb.v, qB1.v);
        }
        __builtin_amdgcn_s_setprio(0);

        // ---- pack p for both chains
        FragU pA0, pA1, pB0, pB1;
        pA0.u[0] = cvl2(acc1A[0][0], acc1A[0][1]);
        pA0.u[1] = cvl2(acc1A[0][2], acc1A[0][3]);
        pA0.u[2] = cvl2(acc1A[1][0], acc1A[1][1]);
        pA0.u[3] = cvl2(acc1A[1][2], acc1A[1][3]);
        pA1.u[0] = cvl2(acc1A[2][0], acc1A[2][1]);
        pA1.u[1] = cvl2(acc1A[2][2], acc1A[2][3]);
        pA1.u[2] = cvl2(acc1A[3][0], acc1A[3][1]);
        pA1.u[3] = cvl2(acc1A[3][2], acc1A[3][3]);
        pB0.u[0] = cvl2(acc1B[0][0], acc1B[0][1]);
        pB0.u[1] = cvl2(acc1B[0][2], acc1B[0][3]);
        pB0.u[2] = cvl2(acc1B[1][0], acc1B[1][1]);
        pB0.u[3] = cvl2(acc1B[1][2], acc1B[1][3]);
        pB1.u[0] = cvl2(acc1B[2][0], acc1B[2][1]);
        pB1.u[1] = cvl2(acc1B[2][2], acc1B[2][3]);
        pB1.u[2] = cvl2(acc1B[3][0], acc1B[3][1]);
        pB1.u[3] = cvl2(acc1B[3][2], acc1B[3][3]);

        // ---- GEMM2 both chains (W2 from LDS)
        __builtin_amdgcn_s_setprio(1);
        f32x4 acc2A[4], acc2B[4];
#pragma unroll
        for (int nf = 0; nf < 4; ++nf) {
            FragU wa, wb;
            wa.q = wlds[widx + (8 + nf) * 64 + l];
            wb.q = wlds[widx + (12 + nf) * 64 + l];
            acc2A[nf] = mfma_init(wa.v, pA0.v, b2f[nf]);
            acc2B[nf] = mfma_init(wa.v, pB0.v, b2f[nf]);
            mfma_acc(acc2A[nf], wb.v, pA1.v);
            mfma_acc(acc2B[nf], wb.v, pB1.v);
        }
        __builtin_amdgcn_s_setprio(0);

        // ---- fused lrel-agg for both chains (shared accumulator)
#pragma unroll
        for (int nf = 0; nf < 4; ++nf)
#pragma unroll
            for (int r = 0; r < 4; ++r) {
                aggfma(aggL[nf][r], acc2A[nf][r]);
                aggfma(aggL[nf][r], acc2B[nf][r]);
            }

        xjA = xjAn;
        xjB = xjBn;
    }

    // ---- reduce over the 16 edge-lanes (lo); lanes lo==0 hold full sums
#pragma unroll
    for (int nf = 0; nf < 4; ++nf)
#pragma unroll
        for (int r = 0; r < 4; ++r) {
            float v = aggL[nf][r];
            v += __shfl_xor(v, 1);
            v += __shfl_xor(v, 2);
            v += __shfl_xor(v, 4);
            v += __shfl_xor(v, 8);
            aggL[nf][r] = v;
        }
    if (lo == 0) {
#pragma unroll
        for (int nf = 0; nf < 4; ++nf) {
            float4 o = {aggL[nf][0], aggL[nf][1], aggL[nf][2], aggL[nf][3]};
            *(float4*)(AGG + node * 64 + 16 * nf + 4 * g) = o;
        }
    }
}

// ---------------- Kernel 3: node MLP fn: [agg, x] -> 128 -> 128 -> 32 ----------------
__global__ __launch_bounds__(256) void k_fn(
    const float* __restrict__ AGG, const float* __restrict__ x,
    const float* __restrict__ W0, const float* __restrict__ b0,
    const float* __restrict__ W1, const float* __restrict__ b1,
    const float* __restrict__ W2, const float* __restrict__ b2,
    float* __restrict__ out)
{
    __shared__ float in96T[96][8];
    __shared__ float h1T[128][8];
    __shared__ float h2T[128][8];
    const int t = threadIdx.x;
    const int half = t >> 7, f = t & 127;
    const int node0 = blockIdx.x * 8;

    for (int idx = t; idx < 768; idx += 256) {
        int nn = idx & 7, k = idx >> 3;
        in96T[k][nn] = (k < 64) ? AGG[(node0 + nn) * 64 + k]
                                : x[(node0 + nn) * 32 + (k - 64)];
    }
    __syncthreads();

    {
        float a0 = b0[f], a1 = a0, a2 = a0, a3 = a0;
#pragma unroll 4
        for (int k = 0; k < 96; ++k) {
            const float4 iv = *(const float4*)(&in96T[k][4 * half]);
            const float wv = W0[k * 128 + f];
            a0 += iv.x * wv; a1 += iv.y * wv; a2 += iv.z * wv; a3 += iv.w * wv;
        }
        float4 o = {lrel(a0), lrel(a1), lrel(a2), lrel(a3)};
        *(float4*)(&h1T[f][4 * half]) = o;
    }
    __syncthreads();

    {
        float a0 = b1[f], a1 = a0, a2 = a0, a3 = a0;
#pragma unroll 4
        for (int k = 0; k < 128; ++k) {
            const float4 iv = *(const float4*)(&h1T[k][4 * half]);
            const float wv = W1[k * 128 + f];
            a0 += iv.x * wv; a1 += iv.y * wv; a2 += iv.z * wv; a3 += iv.w * wv;
        }
        float4 o = {lrel(a0), lrel(a1), lrel(a2), lrel(a3)};
        *(float4*)(&h2T[f][4 * half]) = o;
    }
    __syncthreads();

    {
        const int nn = t >> 5, fo = t & 31;
        float a = b2[fo];
#pragma unroll 4
        for (int k = 0; k < 128; ++k) a += h2T[k][nn] * W2[k * 32 + fo];
        out[(node0 + nn) * 32 + fo] = a;
    }
}

extern "C" void kernel_launch(void* const* d_in, const int* in_sizes, int n_in,
                              void* d_out, int out_size, void* d_ws, size_t ws_size,
                              hipStream_t stream)
{
    const float* x    = (const float*)d_in[0];
    const float* feW0 = (const float*)d_in[1];
    const float* feb0 = (const float*)d_in[2];
    const float* feW1 = (const float*)d_in[3];
    const float* feb1 = (const float*)d_in[4];
    const float* feW2 = (const float*)d_in[5];
    const float* feb2 = (const float*)d_in[6];
    const float* fnW0 = (const float*)d_in[7];
    const float* fnb0 = (const float*)d_in[8];
    const float* fnW1 = (const float*)d_in[9];
    const float* fnb1 = (const float*)d_in[10];
    const float* fnW2 = (const float*)d_in[11];
    const float* fnb2 = (const float*)d_in[12];
    float* out = (float*)d_out;

    // workspace: Upi (1MB) | AGG (1MB) | xbf (256KB) | WF (20KB)
    float* Upi = (float*)d_ws;
    float* AGG = Upi + 262144;
    unsigned short* xbf = (unsigned short*)(AGG + 262144);
    unsigned int* WF = (unsigned int*)(xbf + 131072);

    hipLaunchKernelGGL(k_uv,   dim3(1025), dim3(256), 0, stream, x, feW0, feb0, feW1, feW2, Upi, xbf, WF);
    hipLaunchKernelGGL(k_edge, dim3(1024), dim3(256), 0, stream, Upi, xbf, WF, feb1, feb2, AGG);
    hipLaunchKernelGGL(k_fn,   dim3(512),  dim3(256), 0, stream, AGG, x, fnW0, fnb0, fnW1, fnb1, fnW2, fnb2, out);
}